// Round 1
// 66.190 us; speedup vs baseline: 1.0120x; 1.0120x over previous
//
#include <hip/hip_runtime.h>
#include <math.h>

#define NCLS   100
#define ITERS  100
#define RPB    16            // batch rows per block (MFMA M)
#define XS     136           // LDS x row stride, bf16 elems
#define XBUF   (RPB * XS)

typedef short  bf16x8 __attribute__((ext_vector_type(8)));   // 8 bf16 in 4 VGPRs
typedef float  f32x4  __attribute__((ext_vector_type(4)));

#if __has_builtin(__builtin_amdgcn_rcpf)
__device__ __forceinline__ float fast_rcp(float x) { return __builtin_amdgcn_rcpf(x); }
#else
__device__ __forceinline__ float fast_rcp(float x) { return 1.0f / x; }
#endif

#if __has_builtin(__builtin_amdgcn_exp2f)
__device__ __forceinline__ float fast_exp2(float x) { return __builtin_amdgcn_exp2f(x); }
#else
__device__ __forceinline__ float fast_exp2(float x) { return exp2f(x); }
#endif

__device__ __forceinline__ unsigned bf16_rne(float f) {   // f32 -> bf16 bits, RNE
    unsigned u = __float_as_uint(f);
    return (u + 0x7FFFu + ((u >> 16) & 1u)) >> 16;
}
__device__ __forceinline__ float wave_sum(float v) {
#pragma unroll
    for (int m = 32; m > 0; m >>= 1) v += __shfl_xor(v, m, 64);
    return v;
}
__device__ __forceinline__ bool any_ne(f32x4 a, f32x4 b) {
    return (a[0] != b[0]) | (a[1] != b[1]) | (a[2] != b[2]) | (a[3] != b[3]);
}

#define MFMA_B(Af, Bf, Cf) __builtin_amdgcn_mfma_f32_16x16x32_bf16(Af, Bf, Cf, 0, 0, 0)

extern "C" __global__ void sk_zero_out(float* out) { out[0] = 0.0f; }

// One Sinkhorn half-iteration, ONE N-tile per wave (8-wave version).
// X = MG ./ (K x_src); writes bf16 X to DST, exports fp32 X into X0V and the
// raw MFMA acc into accP0_. Same op order as the 4-wave version per element,
// so iterates are bit-identical.
#define HALF(SRC, DST, MG0, X0V)                                             \
    {                                                                        \
        bf16x8 A_[4];                                                        \
        _Pragma("unroll")                                                    \
        for (int s_ = 0; s_ < 4; ++s_)                                       \
            A_[s_] = *(const bf16x8*)((SRC) + lc * XS + s_ * 32 + quad * 8); \
        f32x4 aA_ = {0,0,0,0}, aB_ = {0,0,0,0};                              \
        aA_ = MFMA_B(A_[0], B0[0], aA_);                                     \
        aB_ = MFMA_B(A_[2], B0[2], aB_);                                     \
        aA_ = MFMA_B(A_[1], B0[1], aA_);                                     \
        aB_ = MFMA_B(A_[3], B0[3], aB_);                                     \
        f32x4 acc0_ = aA_ + aB_;                                             \
        _Pragma("unroll")                                                    \
        for (int r_ = 0; r_ < 4; ++r_) {                                     \
            int m_ = quad * 4 + r_;                                          \
            X0V[r_] = MG0[r_] * fast_rcp(acc0_[r_] + bias0);                 \
            (DST)[m_ * XS + t0n] = (short)bf16_rne(X0V[r_]);                 \
        }                                                                    \
        accP0_ = acc0_;                                                      \
    }

// ---------------------------------------------------------------------------
// Fully fused Sinkhorn. 8 waves (512 threads) per 16-row block: wave w owns
// N-tile w (N pad 128). Same MFMA total as the 4-wave version but 2 waves/SIMD
// (latency hiding) and half the per-wave issue work on the serial chain.
// Early exit on odd-half MFMA acc bf16-bit-stationarity (R13-verified logic).
// ---------------------------------------------------------------------------
extern "C" __global__ void __launch_bounds__(512, 2)
sk_fused(const float* __restrict__ pred, const int* __restrict__ target,
         float* __restrict__ out, int rows)
{
    __shared__ short xs[2 * XBUF];
    __shared__ __align__(16) float aux[RPB * 104];  // muL pre-loop; SsumP/zP/sclS post
    __shared__ __align__(8) unsigned char flagC[8]; // per-wave change flags, 1 u64 read

    const int tid  = threadIdx.x;
    const int lane = tid & 63;
    const int wave = tid >> 6;        // 0..7
    const int quad = lane >> 4;       // 0..3
    const int lc   = lane & 15;
    const int row0 = blockIdx.x * RPB;

    // ---- mu = normalize(softmax(pred_row) + STAB): 16 threads per row ----
    // (kept on tid<256 with the exact 4-wave lane mapping => mu is bit-exact)
    if (tid < 256) {
        const int r = tid >> 4;       // 0..15
        const int c = tid & 15;
        const float* p = pred + (size_t)(row0 + r) * NCLS;
        const float l2e = 1.44269504089f;
        float v[7];
        float mx = -3.4e38f;
#pragma unroll
        for (int q = 0; q < 7; ++q) {
            int j = c + q * 16;
            v[q] = (j < NCLS) ? p[j] : -3.4e38f;
            mx = fmaxf(mx, v[q]);
        }
#pragma unroll
        for (int m = 8; m >= 1; m >>= 1) mx = fmaxf(mx, __shfl_xor(mx, m, 64));
        float s = 0.f;
#pragma unroll
        for (int q = 0; q < 7; ++q) {
            v[q] = (c + q * 16 < NCLS) ? fast_exp2((v[q] - mx) * l2e) : 0.f;
            s += v[q];
        }
#pragma unroll
        for (int m = 8; m >= 1; m >>= 1) s += __shfl_xor(s, m, 64);
        float invS = 1.f / s;
        float s2 = 0.f;
#pragma unroll
        for (int q = 0; q < 7; ++q) {
            if (c + q * 16 < NCLS) { v[q] = v[q] * invS + 1e-6f; s2 += v[q]; }
        }
#pragma unroll
        for (int m = 8; m >= 1; m >>= 1) s2 += __shfl_xor(s2, m, 64);
        float invM = 1.f / s2;
#pragma unroll
        for (int q = 0; q < 7; ++q) {
            int j = c + q * 16;
            if (j < NCLS) aux[r * 104 + j] = v[q] * invM;
        }
    }

    // ---- this wave's N-columns (one 16-col tile) ----
    const int t0n = wave * 16 + lc;
    const float bias0 = (t0n >= NCLS) ? 1.0f : 0.0f;   // keep rcp input > 0 on pad cols

    // ---- static B-fragments: B[k=quad*8+j][n] = w(k-n), bf16, Toeplitz ----
    const float c2 = -14.4269504089f / 9801.0f;        // -10*log2(e)/9801
    bf16x8 B0[4];
#pragma unroll
    for (int s = 0; s < 4; ++s) {
#pragma unroll
        for (int j = 0; j < 8; ++j) {
            int k  = s * 32 + quad * 8 + j;
            int d0 = k - t0n;
            B0[s][j] = (short)bf16_rne(fast_exp2(c2 * (float)(d0 * d0)));
        }
    }

    __syncthreads();   // muL ready

    // ---- marginal fragments in C-layout (row m = quad*4+r, col n=t0n) ----
    f32x4 mu0f, nu0f;
    const float invN = 1.0f / (1.0f + (float)NCLS * 1e-6f);
#pragma unroll
    for (int r = 0; r < 4; ++r) {
        int m = quad * 4 + r;
        mu0f[r] = (t0n < NCLS) ? aux[m * 104 + t0n] : 0.f;
        int tg = (int)target[row0 + m];
        nu0f[r] = (t0n < NCLS) ? ((((t0n == tg) ? 1.f : 0.f) + 1e-6f) * invN) : 0.f;
    }

    // ---- WARM START: x = b0 = nu (pad cols 0); buffer 0 ----
#pragma unroll
    for (int r = 0; r < 4; ++r) {
        int m = quad * 4 + r;
        xs[m * XS + t0n] = (short)bf16_rne(nu0f[r]);
    }
    __syncthreads();

    // ---- main pair loop with odd-half stationarity early-exit (<= 99 pairs) ----
    f32x4 pvO0 = {-1.f, -1.f, -1.f, -1.f};
    f32x4 xT0, accP0_;
    for (int pair = 0; pair < ITERS - 1; ++pair) {
        // even half: a = mu/(K b), buf0 -> buf1
        HALF(xs, xs + XBUF, mu0f, xT0);
        __syncthreads();
        // odd half: b = nu/(K a), buf1 -> buf0
        HALF(xs + XBUF, xs, nu0f, xT0);
        bool chgO = any_ne(accP0_, pvO0);
        pvO0 = accP0_;
        int anyv = __any((int)chgO);
        if (lane == 0) flagC[wave] = (unsigned char)anyv;
        __syncthreads();
        if (*(const unsigned long long*)flagC == 0ULL) break;
    }

    // ---- capture pair: final a (fp32) and b (fp32); b bf16 lands in buf0 ----
    f32x4 aR0, bR0, accT;
    HALF(xs, xs + XBUF, mu0f, aR0);
    __syncthreads();
    HALF(xs + XBUF, xs, nu0f, bR0);
    __syncthreads();
    (void)accT;

    // ================= fused epilogue (round-10-verified math) =================
    // t = K b  (A from buffer 0)
    f32x4 t0a = {0.f, 0.f, 0.f, 0.f};
    {
        bf16x8 A[4];
#pragma unroll
        for (int s = 0; s < 4; ++s)
            A[s] = *(const bf16x8*)(xs + lc * XS + s * 32 + quad * 8);
#pragma unroll
        for (int s = 0; s < 4; ++s)
            t0a = MFMA_B(A[s], B0[s], t0a);
    }

    // scl = mu / (a*t + n*STAB);  a' = a*scl.  Write a' (buf1) and scl bf16.
    float* SsumP = aux;                     // [8 waves][16 m] floats (512 B)
    float* zP    = aux + 128;               // [8] block-reduce slots
    short* sclS  = (short*)(aux + 136);     // [RPB][XS] bf16 (4352 B), 16B-aligned
    short* apS   = xs + XBUF;               // buffer 1, a dead

#pragma unroll
    for (int r = 0; r < 4; ++r) {
        int m = quad * 4 + r;
        float scl0 = mu0f[r] * fast_rcp(fmaf(aR0[r], t0a[r], (float)NCLS * 1e-6f));
        apS[m * XS + t0n]  = (short)bf16_rne(aR0[r] * scl0);
        sclS[m * XS + t0n] = (short)bf16_rne(scl0);
        // partial Ssum over this wave's 16 cols (16-lane quad reduce)
        float ps = scl0;
#pragma unroll
        for (int w = 8; w >= 1; w >>= 1) ps += __shfl_xor(ps, w, 64);
        if (lc == 0) SsumP[wave * 16 + m] = ps;
    }
    __syncthreads();

    // Ssum[m] = sum over 8 waves
    f32x4 Ssum;
#pragma unroll
    for (int r = 0; r < 4; ++r) {
        int m = quad * 4 + r;
        float acc = 0.f;
#pragma unroll
        for (int w = 0; w < 8; ++w) acc += SsumP[w * 16 + m];
        Ssum[r] = acc;
    }

    // B-frags for K.C and C (Toeplitz): KC(d) = K(d)*d^2/9801, C(d) = d^2/9801
    bf16x8 KC0[4], C0[4];
    const float cinv = 1.0f / 9801.0f;
#pragma unroll
    for (int s = 0; s < 4; ++s) {
#pragma unroll
        for (int j = 0; j < 8; ++j) {
            int k  = s * 32 + quad * 8 + j;
            int d0 = k - t0n;
            float cc = (float)(d0 * d0) * cinv;
            KC0[s][j] = (short)bf16_rne(fast_exp2(c2 * (float)(d0 * d0)) * cc);
            C0[s][j]  = (short)bf16_rne(cc);
        }
    }

    // q = K a',  mm = (K.C) a',  cs = C scl   (A-frags from apS / sclS)
    f32x4 qv = {0,0,0,0}, mv = {0,0,0,0}, sv = {0,0,0,0};
    {
        bf16x8 Aa[4], As[4];
#pragma unroll
        for (int s = 0; s < 4; ++s) {
            Aa[s] = *(const bf16x8*)(apS  + lc * XS + s * 32 + quad * 8);
            As[s] = *(const bf16x8*)(sclS + lc * XS + s * 32 + quad * 8);
        }
#pragma unroll
        for (int s = 0; s < 4; ++s) {
            qv = MFMA_B(Aa[s], B0[s],  qv);
            mv = MFMA_B(Aa[s], KC0[s], mv);
            sv = MFMA_B(As[s], C0[s],  sv);
        }
    }

    // cost: z = sum_j nu_j/(b_j q_j + STAB*Ssum) * (b_j mm_j + STAB*cs_j)
    float z = 0.f;
#pragma unroll
    for (int r = 0; r < 4; ++r) {
        float col0 = fmaf(bR0[r], qv[r], 1e-6f * Ssum[r]);
        float in0  = fmaf(bR0[r], mv[r], 1e-6f * sv[r]);
        z += nu0f[r] * fast_rcp(col0) * in0;
    }
    z = wave_sum(z);
    if (lane == 0) zP[wave] = z;
    __syncthreads();
    if (tid == 0) {
        float tot = zP[0] + zP[1] + zP[2] + zP[3] + zP[4] + zP[5] + zP[6] + zP[7];
        atomicAdd(out, tot / (float)rows);
    }
}

extern "C" void kernel_launch(void* const* d_in, const int* in_sizes, int n_in,
                              void* d_out, int out_size, void* d_ws, size_t ws_size,
                              hipStream_t stream)
{
    const float* pred   = (const float*)d_in[0];
    const int*   target = (const int*)d_in[1];
    float*       out    = (float*)d_out;
    const int    rows   = in_sizes[0] / NCLS;   // 4096

    hipLaunchKernelGGL(sk_zero_out, dim3(1), dim3(1), 0, stream, out);
    hipLaunchKernelGGL(sk_fused, dim3(rows / RPB), dim3(512), 0, stream,
                       pred, target, out, rows);
}

// Round 2
// 64.456 us; speedup vs baseline: 1.0393x; 1.0269x over previous
//
#include <hip/hip_runtime.h>
#include <math.h>

#define NCLS   100
#define ITERS  100
#define RPB    16            // batch rows per block (MFMA N now)
#define KS     136           // LDS class-dim stride, bf16 elems (row-major X[m][k])
#define XBUF   (RPB * KS)

typedef short  bf16x8 __attribute__((ext_vector_type(8)));   // 8 bf16 in 4 VGPRs
typedef float  f32x4  __attribute__((ext_vector_type(4)));

#if __has_builtin(__builtin_amdgcn_rcpf)
__device__ __forceinline__ float fast_rcp(float x) { return __builtin_amdgcn_rcpf(x); }
#else
__device__ __forceinline__ float fast_rcp(float x) { return 1.0f / x; }
#endif

#if __has_builtin(__builtin_amdgcn_exp2f)
__device__ __forceinline__ float fast_exp2(float x) { return __builtin_amdgcn_exp2f(x); }
#else
__device__ __forceinline__ float fast_exp2(float x) { return exp2f(x); }
#endif

__device__ __forceinline__ unsigned bf16_rne(float f) {   // f32 -> bf16 bits, RNE
    unsigned u = __float_as_uint(f);
    return (u + 0x7FFFu + ((u >> 16) & 1u)) >> 16;
}
// packed f32x2 -> bf16x2 (RNE), dword.lo = bf16(a), dword.hi = bf16(b)
__device__ __forceinline__ unsigned cvt_pk_bf16(float a, float b) {
    unsigned r;
    asm("v_cvt_pk_bf16_f32 %0, %1, %2" : "=v"(r) : "v"(a), "v"(b));
    return r;
}
__device__ __forceinline__ float wave_sum(float v) {
#pragma unroll
    for (int m = 32; m > 0; m >>= 1) v += __shfl_xor(v, m, 64);
    return v;
}
__device__ __forceinline__ bool any_ne(f32x4 a, f32x4 b) {
    return (a[0] != b[0]) | (a[1] != b[1]) | (a[2] != b[2]) | (a[3] != b[3]);
}

#define MFMA_B(Af, Bf, Cf) __builtin_amdgcn_mfma_f32_16x16x32_bf16(Af, Bf, Cf, 0, 0, 0)

extern "C" __global__ void sk_zero_out(float* out) { out[0] = 0.0f; }

// One Sinkhorn half-iteration, TRANSPOSED: computes Xnew^T[n][m] with
// A = static Toeplitz W-fragment (rows n), B = X_old read from LDS (same
// address expression as the old A-read; LDS layout X[m][k] unchanged).
// C's 4 regs now span the CLASS dim -> 4 contiguous LDS elems -> one
// packed ds_write_b64 (2x v_cvt_pk_bf16_f32) instead of 16 VALU + 4 b16
// stores. Pad-row bias folded into MFMA C-init (bit-identical on real rows).
#define HALF(SRC, DST, MG0, X0V)                                              \
    {                                                                         \
        bf16x8 Xf_[4];                                                        \
        _Pragma("unroll")                                                     \
        for (int s_ = 0; s_ < 4; ++s_)                                        \
            Xf_[s_] = *(const bf16x8*)((SRC) + lc * KS + s_ * 32 + quad * 8); \
        f32x4 aA_ = biasv;                                                    \
        f32x4 aB_ = {0, 0, 0, 0};                                             \
        aA_ = MFMA_B(W0[0], Xf_[0], aA_);                                     \
        aB_ = MFMA_B(W0[2], Xf_[2], aB_);                                     \
        aA_ = MFMA_B(W0[1], Xf_[1], aA_);                                     \
        aB_ = MFMA_B(W0[3], Xf_[3], aB_);                                     \
        f32x4 acc0_ = aA_ + aB_;                                              \
        _Pragma("unroll")                                                     \
        for (int r_ = 0; r_ < 4; ++r_)                                        \
            X0V[r_] = MG0[r_] * fast_rcp(acc0_[r_]);                          \
        uint2 pk_;                                                            \
        pk_.x = cvt_pk_bf16(X0V[0], X0V[1]);                                  \
        pk_.y = cvt_pk_bf16(X0V[2], X0V[3]);                                  \
        *(uint2*)((DST) + wq4) = pk_;                                         \
        accP0_ = acc0_;                                                       \
    }

// ---------------------------------------------------------------------------
// Fully fused Sinkhorn, transposed-iterate formulation. 8 waves (512 thr)
// per 16-row block; wave w owns class rows [16w,16w+16). Early exit on
// odd-half raw-acc bf16 bit-stationarity (layout-independent, R13 logic).
// ---------------------------------------------------------------------------
extern "C" __global__ void __launch_bounds__(512, 2)
sk_fused(const float* __restrict__ pred, const int* __restrict__ target,
         float* __restrict__ out, int rows)
{
    __shared__ short xs[2 * XBUF];
    __shared__ __align__(16) float aux[RPB * 104];  // muL pre-loop; SsumP/zP/sclS post
    __shared__ __align__(8) unsigned char flagC[8]; // per-wave change flags, 1 u64 read

    const int tid  = threadIdx.x;
    const int lane = tid & 63;
    const int wave = tid >> 6;        // 0..7
    const int quad = lane >> 4;       // 0..3
    const int lc   = lane & 15;
    const int row0 = blockIdx.x * RPB;

    // ---- mu = normalize(softmax(pred_row) + STAB): 16 threads per row ----
    if (tid < 256) {
        const int r = tid >> 4;       // 0..15
        const int c = tid & 15;
        const float* p = pred + (size_t)(row0 + r) * NCLS;
        const float l2e = 1.44269504089f;
        float v[7];
        float mx = -3.4e38f;
#pragma unroll
        for (int q = 0; q < 7; ++q) {
            int j = c + q * 16;
            v[q] = (j < NCLS) ? p[j] : -3.4e38f;
            mx = fmaxf(mx, v[q]);
        }
#pragma unroll
        for (int m = 8; m >= 1; m >>= 1) mx = fmaxf(mx, __shfl_xor(mx, m, 64));
        float s = 0.f;
#pragma unroll
        for (int q = 0; q < 7; ++q) {
            v[q] = (c + q * 16 < NCLS) ? fast_exp2((v[q] - mx) * l2e) : 0.f;
            s += v[q];
        }
#pragma unroll
        for (int m = 8; m >= 1; m >>= 1) s += __shfl_xor(s, m, 64);
        float invS = 1.f / s;
        float s2 = 0.f;
#pragma unroll
        for (int q = 0; q < 7; ++q) {
            if (c + q * 16 < NCLS) { v[q] = v[q] * invS + 1e-6f; s2 += v[q]; }
        }
#pragma unroll
        for (int m = 8; m >= 1; m >>= 1) s2 += __shfl_xor(s2, m, 64);
        float invM = 1.f / s2;
#pragma unroll
        for (int q = 0; q < 7; ++q) {
            int j = c + q * 16;
            if (j < NCLS) aux[r * 104 + j] = v[q] * invM;
        }
    }

    // ---- this wave's class rows: lane's A-row n = t0n; regs span n_r ----
    const int t0n = wave * 16 + lc;                 // A-fragment row index
    f32x4 biasv;                                    // pad-ROW bias, folded into C-init
#pragma unroll
    for (int r = 0; r < 4; ++r)
        biasv[r] = (wave * 16 + quad * 4 + r >= NCLS) ? 1.0f : 0.0f;

    // ---- static A-fragments: W0[s][j] = w(k - t0n), k = s*32+quad*8+j ----
    // (identical values to the old B0 — symmetric Toeplitz, now used as A)
    const float c2 = -14.4269504089f / 9801.0f;     // -10*log2(e)/9801
    bf16x8 W0[4];
#pragma unroll
    for (int s = 0; s < 4; ++s) {
#pragma unroll
        for (int j = 0; j < 8; ++j) {
            int k  = s * 32 + quad * 8 + j;
            int d0 = k - t0n;
            W0[s][j] = (short)bf16_rne(fast_exp2(c2 * (float)(d0 * d0)));
        }
    }

    __syncthreads();   // muL ready

    // ---- marginal fragments, transposed C-layout: col m = lc, row n_r ----
    f32x4 mu0f, nu0f;
    const float invN = 1.0f / (1.0f + (float)NCLS * 1e-6f);
    const int tg = (int)target[row0 + lc];
#pragma unroll
    for (int r = 0; r < 4; ++r) {
        int n_r = wave * 16 + quad * 4 + r;
        mu0f[r] = (n_r < NCLS) ? aux[lc * 104 + n_r] : 0.f;
        nu0f[r] = (n_r < NCLS) ? ((((n_r == tg) ? 1.f : 0.f) + 1e-6f) * invN) : 0.f;
    }

    // ---- packed-store address: X[m=lc][k = wave*16+quad*4 .. +3] ----
    const int wq4 = lc * KS + wave * 16 + quad * 4;

    // ---- WARM START: buf0 = b0 = nu (pad rows 0), packed b64 ----
    {
        uint2 pk;
        pk.x = cvt_pk_bf16(nu0f[0], nu0f[1]);
        pk.y = cvt_pk_bf16(nu0f[2], nu0f[3]);
        *(uint2*)(xs + wq4) = pk;
    }
    __syncthreads();

    // ---- main pair loop with odd-half stationarity early-exit (<= 99 pairs) ----
    f32x4 pvO0 = {-1.f, -1.f, -1.f, -1.f};
    f32x4 xT0, accP0_;
    for (int pair = 0; pair < ITERS - 1; ++pair) {
        // even half: a = mu/(K b), buf0 -> buf1
        HALF(xs, xs + XBUF, mu0f, xT0);
        __syncthreads();
        // odd half: b = nu/(K a), buf1 -> buf0
        HALF(xs + XBUF, xs, nu0f, xT0);
        bool chgO = any_ne(accP0_, pvO0);
        pvO0 = accP0_;
        int anyv = __any((int)chgO);
        if (lane == 0) flagC[wave] = (unsigned char)anyv;
        __syncthreads();
        if (*(const unsigned long long*)flagC == 0ULL) break;
    }

    // ---- capture pair: final a (fp32) and b (fp32); b bf16 lands in buf0 ----
    f32x4 aR0, bR0;
    HALF(xs, xs + XBUF, mu0f, aR0);
    __syncthreads();
    HALF(xs + XBUF, xs, nu0f, bR0);
    __syncthreads();

    // ================= fused epilogue (round-10 math, transposed) =============
    // t = K b  (A = W0, B = b from buffer 0)
    f32x4 t0a = {0.f, 0.f, 0.f, 0.f};
    {
        bf16x8 Bf[4];
#pragma unroll
        for (int s = 0; s < 4; ++s)
            Bf[s] = *(const bf16x8*)(xs + lc * KS + s * 32 + quad * 8);
#pragma unroll
        for (int s = 0; s < 4; ++s)
            t0a = MFMA_B(W0[s], Bf[s], t0a);
    }

    // scl = mu / (a*t + n*STAB);  a' = a*scl.  Packed b64 writes.
    float* SsumP = aux;                     // [8 waves][16 m] floats (512 B)
    float* zP    = aux + 128;               // [8] block-reduce slots
    short* sclS  = (short*)(aux + 136);     // [RPB][KS] bf16, 8B-aligned
    short* apS   = xs + XBUF;               // buffer 1, a dead

    f32x4 sclv;
#pragma unroll
    for (int r = 0; r < 4; ++r)
        sclv[r] = mu0f[r] * fast_rcp(fmaf(aR0[r], t0a[r], (float)NCLS * 1e-6f));
    {
        uint2 pa;
        pa.x = cvt_pk_bf16(aR0[0] * sclv[0], aR0[1] * sclv[1]);
        pa.y = cvt_pk_bf16(aR0[2] * sclv[2], aR0[3] * sclv[3]);
        *(uint2*)(apS + wq4) = pa;
        uint2 ps;
        ps.x = cvt_pk_bf16(sclv[0], sclv[1]);
        ps.y = cvt_pk_bf16(sclv[2], sclv[3]);
        *(uint2*)(sclS + wq4) = ps;
    }
    // Ssum[m=lc]: sum scl over class dim = regs + quads + waves
    {
        float ps = sclv[0] + sclv[1] + sclv[2] + sclv[3];
        ps += __shfl_xor(ps, 16, 64);
        ps += __shfl_xor(ps, 32, 64);
        if (lane < 16) SsumP[wave * 16 + lane] = ps;
    }
    __syncthreads();
    float Ssum = 0.f;
#pragma unroll
    for (int w = 0; w < 8; ++w) Ssum += SsumP[w * 16 + lc];

    // A-frags for K.C and C (Toeplitz): KC(d) = K(d)*d^2/9801, C(d) = d^2/9801
    bf16x8 KC0[4], C0[4];
    const float cinv = 1.0f / 9801.0f;
#pragma unroll
    for (int s = 0; s < 4; ++s) {
#pragma unroll
        for (int j = 0; j < 8; ++j) {
            int k  = s * 32 + quad * 8 + j;
            int d0 = k - t0n;
            float cc = (float)(d0 * d0) * cinv;
            KC0[s][j] = (short)bf16_rne(fast_exp2(c2 * (float)(d0 * d0)) * cc);
            C0[s][j]  = (short)bf16_rne(cc);
        }
    }

    // q = K a',  mm = (K.C) a',  cs = C scl   (B-operands from apS / sclS)
    f32x4 qv = {0,0,0,0}, mv = {0,0,0,0}, sv = {0,0,0,0};
    {
        bf16x8 Aa[4], As[4];
#pragma unroll
        for (int s = 0; s < 4; ++s) {
            Aa[s] = *(const bf16x8*)(apS  + lc * KS + s * 32 + quad * 8);
            As[s] = *(const bf16x8*)(sclS + lc * KS + s * 32 + quad * 8);
        }
#pragma unroll
        for (int s = 0; s < 4; ++s) {
            qv = MFMA_B(W0[s],  Aa[s], qv);
            mv = MFMA_B(KC0[s], Aa[s], mv);
            sv = MFMA_B(C0[s],  As[s], sv);
        }
    }

    // cost: z = sum nu/(b*q + STAB*Ssum) * (b*mm + STAB*cs)
    float z = 0.f;
#pragma unroll
    for (int r = 0; r < 4; ++r) {
        float col0 = fmaf(bR0[r], qv[r], 1e-6f * Ssum);
        float in0  = fmaf(bR0[r], mv[r], 1e-6f * sv[r]);
        z += nu0f[r] * fast_rcp(col0) * in0;
    }
    z = wave_sum(z);
    if (lane == 0) zP[wave] = z;
    __syncthreads();
    if (tid == 0) {
        float tot = zP[0] + zP[1] + zP[2] + zP[3] + zP[4] + zP[5] + zP[6] + zP[7];
        atomicAdd(out, tot / (float)rows);
    }
}

extern "C" void kernel_launch(void* const* d_in, const int* in_sizes, int n_in,
                              void* d_out, int out_size, void* d_ws, size_t ws_size,
                              hipStream_t stream)
{
    const float* pred   = (const float*)d_in[0];
    const int*   target = (const int*)d_in[1];
    float*       out    = (float*)d_out;
    const int    rows   = in_sizes[0] / NCLS;   // 4096

    hipLaunchKernelGGL(sk_zero_out, dim3(1), dim3(1), 0, stream, out);
    hipLaunchKernelGGL(sk_fused, dim3(rows / RPB), dim3(512), 0, stream,
                       pred, target, out, rows);
}